// Round 3
// baseline (264.265 us; speedup 1.0000x reference)
//
#include <hip/hip_runtime.h>

#define N_NODES 50000
#define BATCH   4
#define N_EDGES 500000
#define H_SIZE  64

#define NSEG   (BATCH * N_NODES)            // 200,000 segments (b, src)
#define NEDGE  (BATCH * N_EDGES)            // 2,000,000 edges
#define NHEL   ((long long)BATCH * N_NODES * H_SIZE)   // 12.8M H elems

#define SPB    128                          // segments per bucket (seg>>7)
#define CB     ((NSEG + SPB - 1) / SPB)     // 1563 buckets
#define CAP    2048                         // slots per bucket (mean 1280, +21 sigma)
#define OCAP   65536                        // overflow list capacity (normally 0 used)

#define SC_GRID 2048                        // scatter blocks (grid-stride)

// ---------- Phase 1: single-pass slot-reserving scatter + fused cvt ----------
// pair.x = (sl<<18) | gdst  where sl = seg&127, gdst = b*N_NODES+dst (<2^18)
// pair.y = bits(w). Slot reserved via atomicAdd on 64B-padded bucket counter.
__global__ __launch_bounds__(256) void scatter1_kernel(
    const float* __restrict__ ew, int* __restrict__ gcnt16,
    int* __restrict__ ocnt, int4* __restrict__ olist,
    int2* __restrict__ pair,
    const float* __restrict__ H, ushort* __restrict__ Hb16, int do_cvt)
{
    const int nthr = SC_GRID * 256;
    for (int e = blockIdx.x * 256 + threadIdx.x; e < NEDGE; e += nthr) {
        long long eb = (long long)e * 3;
        int b = e / N_EDGES;
        int src = (int)ew[eb];
        int dst = (int)ew[eb + 1];
        float w = ew[eb + 2];
        src = min(max(src, 0), N_NODES - 1);
        dst = min(max(dst, 0), N_NODES - 1);
        int seg  = b * N_NODES + src;
        int gdst = b * N_NODES + dst;
        int cb = seg >> 7, sl = seg & (SPB - 1);
        int pos = atomicAdd(&gcnt16[cb << 4], 1);   // 64B-padded counter
        if (pos < CAP) {
            int2 v; v.x = (sl << 18) | gdst; v.y = __float_as_int(w);
            pair[((long long)cb << 11) + pos] = v;
        } else {
            int op = atomicAdd(ocnt, 1);
            if (op < OCAP) {
                int4 o; o.x = seg; o.y = gdst; o.z = __float_as_int(w); o.w = 0;
                olist[op] = o;
            }
        }
    }

    // fused cvt: H fp32 -> bf16 (RNE), grid-stride
    if (do_cvt) {
        const long long stride = (long long)SC_GRID * 256 * 4;
        for (long long i = ((long long)blockIdx.x * 256 + threadIdx.x) * 4;
             i < NHEL; i += stride) {
            float4 f = *(const float4*)(H + i);
            ushort4 u;
            uint v;
            v = __float_as_uint(f.x); u.x = (ushort)((v + 0x7FFF + ((v >> 16) & 1)) >> 16);
            v = __float_as_uint(f.y); u.y = (ushort)((v + 0x7FFF + ((v >> 16) & 1)) >> 16);
            v = __float_as_uint(f.z); u.z = (ushort)((v + 0x7FFF + ((v >> 16) & 1)) >> 16);
            v = __float_as_uint(f.w); u.w = (ushort)((v + 0x7FFF + ((v >> 16) & 1)) >> 16);
            *(ushort4*)(Hb16 + i) = u;
        }
    }
}

// ---------- Phase 2: fused counting-sort (LDS) + register gather ----------
// One block per bucket. Sort the bucket slab into LDS by segment slot (int
// LDS atomics only), then 8 waves x 16 segments each accumulate in VGPRs:
// half-wave = edge parity, sub-lane = feature pair (uint = 2 bf16 feats).
__global__ __launch_bounds__(512) void sortgather_bf16(
    const ushort* __restrict__ Hb16, const int* __restrict__ gcnt16,
    const int* __restrict__ ocnt, const int4* __restrict__ olist,
    const int2* __restrict__ pair, float* __restrict__ out)
{
    __shared__ int2 sps[CAP];          // 16 KB sorted pairs
    __shared__ int cnt[SPB];
    __shared__ int scn[SPB];
    __shared__ int lcur[SPB];
    const int cb = blockIdx.x;
    const int tid = threadIdx.x;
    const long long base = (long long)cb << 11;   // cb * CAP

    int total = gcnt16[cb << 4];
    int nb = min(max(total, 0), CAP);
    int novf = min(max(*ocnt, 0), OCAP);

    for (int i = tid; i < SPB; i += 512) { cnt[i] = 0; lcur[i] = 0; }
    __syncthreads();
    // pass 1: histogram (warms slab into L1/L2)
    for (int i = tid; i < nb; i += 512) {
        int2 v = pair[base + i];
        atomicAdd(&cnt[(v.x >> 18) & (SPB - 1)], 1);
    }
    __syncthreads();
    // exclusive scan of cnt -> scn
    if (tid < SPB) scn[tid] = cnt[tid];
    __syncthreads();
    for (int off = 1; off < SPB; off <<= 1) {
        int t = (tid < SPB && tid >= off) ? scn[tid - off] : 0;
        __syncthreads();
        if (tid < SPB) scn[tid] += t;
        __syncthreads();
    }
    if (tid < SPB) scn[tid] -= cnt[tid];
    __syncthreads();
    // pass 2: scatter into sorted LDS (slab re-read is cache-hot)
    for (int i = tid; i < nb; i += 512) {
        int2 v = pair[base + i];
        int sl = (v.x >> 18) & (SPB - 1);
        int pos = scn[sl] + atomicAdd(&lcur[sl], 1);
        pos = min(max(pos, 0), CAP - 1);
        sps[pos] = v;
    }
    __syncthreads();

    // gather: wave w owns segments w*16 .. w*16+15
    const int wid  = tid >> 6;
    const int lane = tid & 63;
    const int half = lane >> 5;
    const int sub  = lane & 31;
    const uint* H32 = (const uint*)Hb16;

    for (int s = 0; s < 16; ++s) {
        int sl = wid * 16 + s;
        int st = scn[sl];
        int en = st + cnt[sl];
        float ax = 0.f, ay = 0.f;
        for (int i = st; i < en; i += 4) {
            int e0 = i + half;
            int e1 = i + 2 + half;
            int2 p0 = sps[(e0 < en) ? e0 : st];
            int2 p1 = sps[(e1 < en) ? e1 : st];
            uint a0 = ((uint)(p0.x & 0x3FFFF) << 5) + sub;
            uint a1 = ((uint)(p1.x & 0x3FFFF) << 5) + sub;
            uint h0 = H32[a0];
            uint h1 = H32[a1];
            float w0 = (e0 < en) ? __int_as_float(p0.y) : 0.0f;
            float w1 = (e1 < en) ? __int_as_float(p1.y) : 0.0f;
            ax = fmaf(w0, __uint_as_float(h0 << 16), ax);
            ay = fmaf(w0, __uint_as_float(h0 & 0xFFFF0000u), ay);
            ax = fmaf(w1, __uint_as_float(h1 << 16), ax);
            ay = fmaf(w1, __uint_as_float(h1 & 0xFFFF0000u), ay);
        }
        ax += __shfl_xor(ax, 32, 64);
        ay += __shfl_xor(ay, 32, 64);
        int seg = (cb << 7) + sl;
        if (half == 0 && seg < NSEG) {
            // overflow fold-in (normally novf == 0 -> skipped)
            for (int k = 0; k < novf; ++k) {
                int4 o = olist[k];
                if (o.x == seg) {
                    float w = __int_as_float(o.z);
                    uint hv = H32[((uint)o.y << 5) + sub];
                    ax = fmaf(w, __uint_as_float(hv << 16), ax);
                    ay = fmaf(w, __uint_as_float(hv & 0xFFFF0000u), ay);
                }
            }
            float2 v2; v2.x = ax; v2.y = ay;
            ((float2*)out)[((long long)seg << 5) + sub] = v2;
        }
    }
}

// fp32 variant (workspace too small for the bf16 mirror)
__global__ __launch_bounds__(512) void sortgather_f32(
    const float* __restrict__ H, const int* __restrict__ gcnt16,
    const int* __restrict__ ocnt, const int4* __restrict__ olist,
    const int2* __restrict__ pair, float* __restrict__ out)
{
    __shared__ int2 sps[CAP];
    __shared__ int cnt[SPB];
    __shared__ int scn[SPB];
    __shared__ int lcur[SPB];
    const int cb = blockIdx.x;
    const int tid = threadIdx.x;
    const long long base = (long long)cb << 11;

    int total = gcnt16[cb << 4];
    int nb = min(max(total, 0), CAP);
    int novf = min(max(*ocnt, 0), OCAP);

    for (int i = tid; i < SPB; i += 512) { cnt[i] = 0; lcur[i] = 0; }
    __syncthreads();
    for (int i = tid; i < nb; i += 512) {
        int2 v = pair[base + i];
        atomicAdd(&cnt[(v.x >> 18) & (SPB - 1)], 1);
    }
    __syncthreads();
    if (tid < SPB) scn[tid] = cnt[tid];
    __syncthreads();
    for (int off = 1; off < SPB; off <<= 1) {
        int t = (tid < SPB && tid >= off) ? scn[tid - off] : 0;
        __syncthreads();
        if (tid < SPB) scn[tid] += t;
        __syncthreads();
    }
    if (tid < SPB) scn[tid] -= cnt[tid];
    __syncthreads();
    for (int i = tid; i < nb; i += 512) {
        int2 v = pair[base + i];
        int sl = (v.x >> 18) & (SPB - 1);
        int pos = scn[sl] + atomicAdd(&lcur[sl], 1);
        pos = min(max(pos, 0), CAP - 1);
        sps[pos] = v;
    }
    __syncthreads();

    const int wid  = tid >> 6;
    const int lane = tid & 63;
    const int half = lane >> 5;
    const int sub  = lane & 31;
    const float2* H2 = (const float2*)H;

    for (int s = 0; s < 16; ++s) {
        int sl = wid * 16 + s;
        int st = scn[sl];
        int en = st + cnt[sl];
        float ax = 0.f, ay = 0.f;
        for (int i = st; i < en; i += 4) {
            int e0 = i + half;
            int e1 = i + 2 + half;
            int2 p0 = sps[(e0 < en) ? e0 : st];
            int2 p1 = sps[(e1 < en) ? e1 : st];
            uint a0 = ((uint)(p0.x & 0x3FFFF) << 5) + sub;
            uint a1 = ((uint)(p1.x & 0x3FFFF) << 5) + sub;
            float2 h0 = H2[a0];
            float2 h1 = H2[a1];
            float w0 = (e0 < en) ? __int_as_float(p0.y) : 0.0f;
            float w1 = (e1 < en) ? __int_as_float(p1.y) : 0.0f;
            ax = fmaf(w0, h0.x, ax);
            ay = fmaf(w0, h0.y, ay);
            ax = fmaf(w1, h1.x, ax);
            ay = fmaf(w1, h1.y, ay);
        }
        ax += __shfl_xor(ax, 32, 64);
        ay += __shfl_xor(ay, 32, 64);
        int seg = (cb << 7) + sl;
        if (half == 0 && seg < NSEG) {
            for (int k = 0; k < novf; ++k) {
                int4 o = olist[k];
                if (o.x == seg) {
                    float w = __int_as_float(o.z);
                    float2 hv = H2[((uint)o.y << 5) + sub];
                    ax = fmaf(w, hv.x, ax);
                    ay = fmaf(w, hv.y, ay);
                }
            }
            float2 v2; v2.x = ax; v2.y = ay;
            ((float2*)out)[((long long)seg << 5) + sub] = v2;
        }
    }
}

// ---------- Fallback path (ws too small): zero + atomic scatter ----------
__global__ __launch_bounds__(256) void zero_kernel(int* __restrict__ p, long long n)
{
    long long i = (long long)blockIdx.x * blockDim.x + threadIdx.x;
    if (i < n) p[i] = 0;
}

__global__ __launch_bounds__(256) void atomic_kernel(
    const float* __restrict__ H, const float* __restrict__ ew,
    float* __restrict__ out)
{
    const long long gid = (long long)blockIdx.x * blockDim.x + threadIdx.x;
    const long long wave = gid >> 6;
    const int lane = threadIdx.x & 63;
    if (wave >= (long long)NEDGE) return;
    const int b = (int)(wave / N_EDGES);
    const long long ebase = wave * 3;
    const int src = (int)ew[ebase + 0];
    const int dst = (int)ew[ebase + 1];
    const float w = ew[ebase + 2];
    atomicAdd(&out[((long long)b * N_NODES + src) * H_SIZE + lane],
              w * H[((long long)b * N_NODES + dst) * H_SIZE + lane]);
}

extern "C" void kernel_launch(void* const* d_in, const int* in_sizes, int n_in,
                              void* d_out, int out_size, void* d_ws, size_t ws_size,
                              hipStream_t stream) {
    const float* H  = (const float*)d_in[0];   // (B, N, 64) fp32
    const float* ew = (const float*)d_in[1];   // (B, E, 3) fp32
    float* out = (float*)d_out;                // (B, N, 64) fp32

    // ws layout: gcnt16[CB*16] | ocnt | (16B) olist[OCAP]int4 |
    //            (8B) pair[CB*CAP]int2 | (128B) Hb16[12.8M ushort]
    const size_t cnt_bytes = (size_t)(CB * 16 + 1) * 4;
    const size_t o_off = (cnt_bytes + 15) & ~(size_t)15;
    const size_t p_off = (o_off + (size_t)OCAP * 16 + 7) & ~(size_t)7;
    const size_t h_off = (p_off + (size_t)CB * CAP * 8 + 127) & ~(size_t)127;
    const size_t need2 = h_off;                         // ~26.8 MB (fp32 gather)
    const size_t need1 = h_off + (size_t)NHEL * 2;      // ~52.4 MB (bf16 gather)

    if (ws_size < need2) {
        long long n = out_size;
        zero_kernel<<<(unsigned)((n + 255) / 256), 256, 0, stream>>>((int*)out, n);
        const long long total = (long long)NEDGE * 64;
        atomic_kernel<<<(unsigned)((total + 255) / 256), 256, 0, stream>>>(H, ew, out);
        return;
    }

    int* gcnt16 = (int*)d_ws;
    int* ocnt   = gcnt16 + CB * 16;
    int4* olist = (int4*)((char*)d_ws + o_off);
    int2* pair  = (int2*)((char*)d_ws + p_off);
    ushort* Hb16 = (ushort*)((char*)d_ws + h_off);

    const bool full = (ws_size >= need1);

    hipMemsetAsync(d_ws, 0, cnt_bytes, stream);
    scatter1_kernel<<<SC_GRID, 256, 0, stream>>>(
        ew, gcnt16, ocnt, olist, pair, H, Hb16, full ? 1 : 0);

    if (full) {
        sortgather_bf16<<<CB, 512, 0, stream>>>(Hb16, gcnt16, ocnt, olist, pair, out);
    } else {
        sortgather_f32<<<CB, 512, 0, stream>>>(H, gcnt16, ocnt, olist, pair, out);
    }
}

// Round 4
// 199.032 us; speedup vs baseline: 1.3277x; 1.3277x over previous
//
#include <hip/hip_runtime.h>

#define N_NODES 50000
#define BATCH   4
#define N_EDGES 500000
#define H_SIZE  64

#define NSEG   (BATCH * N_NODES)            // 200,000 segments (b, src)
#define NEDGE  (BATCH * N_EDGES)            // 2,000,000 edges
#define NHEL   ((long long)BATCH * N_NODES * H_SIZE)   // 12.8M H elems

#define SPB    128                          // segments per bucket (seg>>7)
#define CB     ((NSEG + SPB - 1) / SPB)     // 1563 buckets
#define CAP    2048                         // per-bucket LDS edge cap (mean 1280)
#define CHUNK  4096                         // edges per bin block
#define NCHUNK ((NEDGE + CHUNK - 1) / CHUNK) // 489 (<512, fits one scan row)
#define AUXW   (CB + 1)                     // aux row: starts + sentinel
#define BINS   2048                         // padded bin count (>= CB+1)

// ---------- Phase 1: per-chunk bucket binning + fused H->bf16 cvt ----------
// Block c: sort chunk c's edges by bucket in LDS, write them contiguously to
// pair[c*CHUNK ..] (fully coalesced) and the 1564 chunk-local bucket starts
// to aux[c][..] (ushort). Replaces hist+scan1+scan2+scatter with zero global
// atomics and zero write amplification.
// pair.x = (sl<<18) | gdst  where sl = seg&127, gdst = b*N_NODES+dst (<2^18)
__global__ __launch_bounds__(512) void bin_kernel(
    const float* __restrict__ ew, ushort* __restrict__ aux,
    int2* __restrict__ pair,
    const float* __restrict__ H, ushort* __restrict__ Hb16, int do_cvt)
{
    __shared__ int2 st[CHUNK];     // 32 KB sorted staging
    __shared__ int cnt[BINS];      // 8 KB
    __shared__ int scn[BINS];      // 8 KB (starts -> placement cursors)
    __shared__ int ttot[512];      // 2 KB scan temp
    const int c = blockIdx.x;
    const int tid = threadIdx.x;
    const int e0 = c * CHUNK;
    const int n = min(CHUNK, NEDGE - e0);

    for (int i = tid; i < BINS; i += 512) cnt[i] = 0;
    __syncthreads();

    // load up to 8 edges into regs + histogram
    int2 ev[8];
    int  ecb[8];
    int  myn = 0;
    for (int i = tid; i < n; i += 512) {
        long long eb = (long long)(e0 + i) * 3;
        int b = (e0 + i) / N_EDGES;
        int src = (int)ew[eb];
        int dst = (int)ew[eb + 1];
        float w = ew[eb + 2];
        src = min(max(src, 0), N_NODES - 1);
        dst = min(max(dst, 0), N_NODES - 1);
        int seg = b * N_NODES + src;
        int cb = seg >> 7, sl = seg & (SPB - 1);
        int2 v; v.x = (sl << 18) | (b * N_NODES + dst); v.y = __float_as_int(w);
        ev[myn] = v; ecb[myn] = cb; ++myn;
        atomicAdd(&cnt[cb], 1);
    }
    __syncthreads();

    // exclusive scan of 2048 bins: 4 bins/thread + 512-wide scan
    int b0 = cnt[4 * tid], b1 = cnt[4 * tid + 1];
    int b2 = cnt[4 * tid + 2], b3 = cnt[4 * tid + 3];
    int s0 = b0, s01 = b0 + b1, s012 = s01 + b2, tot = s012 + b3;
    ttot[tid] = tot;
    __syncthreads();
    for (int off = 1; off < 512; off <<= 1) {
        int t = (tid >= off) ? ttot[tid - off] : 0;
        __syncthreads();
        ttot[tid] += t;
        __syncthreads();
    }
    int base = ttot[tid] - tot;
    scn[4 * tid]     = base;
    scn[4 * tid + 1] = base + s0;
    scn[4 * tid + 2] = base + s01;
    scn[4 * tid + 3] = base + s012;
    __syncthreads();

    // write chunk-local bucket starts (before cursors get consumed)
    for (int i = tid; i < AUXW; i += 512)
        aux[(long long)c * AUXW + i] = (ushort)scn[i];
    __syncthreads();

    // place edges into sorted LDS staging
    for (int k = 0; k < myn; ++k) {
        int pos = atomicAdd(&scn[ecb[k]], 1);
        st[min(pos, CHUNK - 1)] = ev[k];
    }
    __syncthreads();

    // coalesced writeout (2 edges = int4 per op; n is even for all chunks)
    for (int i = 2 * tid; i + 1 < n; i += 1024)
        *(int4*)(pair + (long long)e0 + i) = *(const int4*)(st + i);
    if (tid == 0 && (n & 1)) pair[(long long)e0 + n - 1] = st[n - 1];

    // fused cvt: H fp32 -> bf16 (RNE), grid-stride
    if (do_cvt) {
        const long long stride = (long long)NCHUNK * 512 * 4;
        for (long long i = ((long long)c * 512 + tid) * 4; i < NHEL; i += stride) {
            float4 f = *(const float4*)(H + i);
            ushort4 u;
            uint v;
            v = __float_as_uint(f.x); u.x = (ushort)((v + 0x7FFF + ((v >> 16) & 1)) >> 16);
            v = __float_as_uint(f.y); u.y = (ushort)((v + 0x7FFF + ((v >> 16) & 1)) >> 16);
            v = __float_as_uint(f.z); u.z = (ushort)((v + 0x7FFF + ((v >> 16) & 1)) >> 16);
            v = __float_as_uint(f.w); u.w = (ushort)((v + 0x7FFF + ((v >> 16) & 1)) >> 16);
            *(ushort4*)(Hb16 + i) = u;
        }
    }
}

// ---------- Phase 2: fused counting-sort (LDS) + register gather ----------
// Block cb gathers its runs from all chunks (thread t = chunk t), stages them
// in LDS, counting-sorts by segment slot (int LDS atomics only), then 8 waves
// x 16 segments accumulate in VGPRs: half-wave = edge parity, sub-lane =
// feature pair (uint = 2 bf16 feats).
__global__ __launch_bounds__(512) void sortgather_bf16(
    const ushort* __restrict__ Hb16, const ushort* __restrict__ aux,
    const int2* __restrict__ pair, float* __restrict__ out)
{
    __shared__ int2 spu[CAP];          // 16 KB unsorted staging
    __shared__ int2 sps[CAP];          // 16 KB sorted
    __shared__ int rb[512];            // run-base scan
    __shared__ int cnt[SPB];
    __shared__ int scn[SPB];
    __shared__ int lcur[SPB];
    const int cb = blockIdx.x;
    const int tid = threadIdx.x;

    // run descriptor for chunk tid
    int off0 = 0, len = 0;
    if (tid < NCHUNK) {
        int a0 = (int)aux[(long long)tid * AUXW + cb];
        int a1 = (int)aux[(long long)tid * AUXW + cb + 1];
        a0 = min(a0, CHUNK); a1 = min(a1, CHUNK);
        off0 = a0; len = max(a1 - a0, 0);
    }
    rb[tid] = len;
    __syncthreads();
    for (int off = 1; off < 512; off <<= 1) {
        int t = (tid >= off) ? rb[tid - off] : 0;
        __syncthreads();
        rb[tid] += t;
        __syncthreads();
    }
    const int mybase = rb[tid] - len;
    const int nb = min(rb[511], CAP);

    for (int i = tid; i < SPB; i += 512) { cnt[i] = 0; lcur[i] = 0; }
    __syncthreads();

    // copy runs into LDS + bin histogram (single global pass)
    const int2* run = pair + (long long)tid * CHUNK + off0;
    for (int k = 0; k < len; ++k) {
        if (mybase + k >= CAP) break;
        int2 v = run[k];
        spu[mybase + k] = v;
        atomicAdd(&cnt[(v.x >> 18) & (SPB - 1)], 1);
    }
    __syncthreads();

    // exclusive scan of bins
    if (tid < SPB) scn[tid] = cnt[tid];
    __syncthreads();
    for (int off = 1; off < SPB; off <<= 1) {
        int t = (tid < SPB && tid >= off) ? scn[tid - off] : 0;
        __syncthreads();
        if (tid < SPB) scn[tid] += t;
        __syncthreads();
    }
    if (tid < SPB) scn[tid] -= cnt[tid];
    __syncthreads();

    // LDS -> LDS counting sort
    for (int i = tid; i < nb; i += 512) {
        int2 v = spu[i];
        int sl = (v.x >> 18) & (SPB - 1);
        int pos = scn[sl] + atomicAdd(&lcur[sl], 1);
        pos = min(max(pos, 0), CAP - 1);
        sps[pos] = v;
    }
    __syncthreads();

    // gather: wave w owns segments w*16 .. w*16+15
    const int wid  = tid >> 6;
    const int lane = tid & 63;
    const int half = lane >> 5;
    const int sub  = lane & 31;
    const uint* H32 = (const uint*)Hb16;

    for (int s = 0; s < 16; ++s) {
        int sl = wid * 16 + s;
        int st = scn[sl];
        int en = st + cnt[sl];
        float ax = 0.f, ay = 0.f;
        for (int i = st; i < en; i += 4) {
            int e0 = i + half;
            int e1 = i + 2 + half;
            int2 p0 = sps[(e0 < en) ? e0 : st];
            int2 p1 = sps[(e1 < en) ? e1 : st];
            uint a0 = ((uint)(p0.x & 0x3FFFF) << 5) + sub;
            uint a1 = ((uint)(p1.x & 0x3FFFF) << 5) + sub;
            uint h0 = H32[a0];
            uint h1 = H32[a1];
            float w0 = (e0 < en) ? __int_as_float(p0.y) : 0.0f;
            float w1 = (e1 < en) ? __int_as_float(p1.y) : 0.0f;
            ax = fmaf(w0, __uint_as_float(h0 << 16), ax);
            ay = fmaf(w0, __uint_as_float(h0 & 0xFFFF0000u), ay);
            ax = fmaf(w1, __uint_as_float(h1 << 16), ax);
            ay = fmaf(w1, __uint_as_float(h1 & 0xFFFF0000u), ay);
        }
        ax += __shfl_xor(ax, 32, 64);
        ay += __shfl_xor(ay, 32, 64);
        int seg = (cb << 7) + sl;
        if (half == 0 && seg < NSEG) {
            float2 v2; v2.x = ax; v2.y = ay;
            ((float2*)out)[((long long)seg << 5) + sub] = v2;
        }
    }
}

// fp32 variant (workspace too small for the bf16 mirror)
__global__ __launch_bounds__(512) void sortgather_f32(
    const float* __restrict__ H, const ushort* __restrict__ aux,
    const int2* __restrict__ pair, float* __restrict__ out)
{
    __shared__ int2 spu[CAP];
    __shared__ int2 sps[CAP];
    __shared__ int rb[512];
    __shared__ int cnt[SPB];
    __shared__ int scn[SPB];
    __shared__ int lcur[SPB];
    const int cb = blockIdx.x;
    const int tid = threadIdx.x;

    int off0 = 0, len = 0;
    if (tid < NCHUNK) {
        int a0 = (int)aux[(long long)tid * AUXW + cb];
        int a1 = (int)aux[(long long)tid * AUXW + cb + 1];
        a0 = min(a0, CHUNK); a1 = min(a1, CHUNK);
        off0 = a0; len = max(a1 - a0, 0);
    }
    rb[tid] = len;
    __syncthreads();
    for (int off = 1; off < 512; off <<= 1) {
        int t = (tid >= off) ? rb[tid - off] : 0;
        __syncthreads();
        rb[tid] += t;
        __syncthreads();
    }
    const int mybase = rb[tid] - len;
    const int nb = min(rb[511], CAP);

    for (int i = tid; i < SPB; i += 512) { cnt[i] = 0; lcur[i] = 0; }
    __syncthreads();

    const int2* run = pair + (long long)tid * CHUNK + off0;
    for (int k = 0; k < len; ++k) {
        if (mybase + k >= CAP) break;
        int2 v = run[k];
        spu[mybase + k] = v;
        atomicAdd(&cnt[(v.x >> 18) & (SPB - 1)], 1);
    }
    __syncthreads();

    if (tid < SPB) scn[tid] = cnt[tid];
    __syncthreads();
    for (int off = 1; off < SPB; off <<= 1) {
        int t = (tid < SPB && tid >= off) ? scn[tid - off] : 0;
        __syncthreads();
        if (tid < SPB) scn[tid] += t;
        __syncthreads();
    }
    if (tid < SPB) scn[tid] -= cnt[tid];
    __syncthreads();

    for (int i = tid; i < nb; i += 512) {
        int2 v = spu[i];
        int sl = (v.x >> 18) & (SPB - 1);
        int pos = scn[sl] + atomicAdd(&lcur[sl], 1);
        pos = min(max(pos, 0), CAP - 1);
        sps[pos] = v;
    }
    __syncthreads();

    const int wid  = tid >> 6;
    const int lane = tid & 63;
    const int half = lane >> 5;
    const int sub  = lane & 31;
    const float2* H2 = (const float2*)H;

    for (int s = 0; s < 16; ++s) {
        int sl = wid * 16 + s;
        int st = scn[sl];
        int en = st + cnt[sl];
        float ax = 0.f, ay = 0.f;
        for (int i = st; i < en; i += 4) {
            int e0 = i + half;
            int e1 = i + 2 + half;
            int2 p0 = sps[(e0 < en) ? e0 : st];
            int2 p1 = sps[(e1 < en) ? e1 : st];
            uint a0 = ((uint)(p0.x & 0x3FFFF) << 5) + sub;
            uint a1 = ((uint)(p1.x & 0x3FFFF) << 5) + sub;
            float2 h0 = H2[a0];
            float2 h1 = H2[a1];
            float w0 = (e0 < en) ? __int_as_float(p0.y) : 0.0f;
            float w1 = (e1 < en) ? __int_as_float(p1.y) : 0.0f;
            ax = fmaf(w0, h0.x, ax);
            ay = fmaf(w0, h0.y, ay);
            ax = fmaf(w1, h1.x, ax);
            ay = fmaf(w1, h1.y, ay);
        }
        ax += __shfl_xor(ax, 32, 64);
        ay += __shfl_xor(ay, 32, 64);
        int seg = (cb << 7) + sl;
        if (half == 0 && seg < NSEG) {
            float2 v2; v2.x = ax; v2.y = ay;
            ((float2*)out)[((long long)seg << 5) + sub] = v2;
        }
    }
}

// ---------- Fallback path (ws too small): zero + atomic scatter ----------
__global__ __launch_bounds__(256) void zero_kernel(int* __restrict__ p, long long n)
{
    long long i = (long long)blockIdx.x * blockDim.x + threadIdx.x;
    if (i < n) p[i] = 0;
}

__global__ __launch_bounds__(256) void atomic_kernel(
    const float* __restrict__ H, const float* __restrict__ ew,
    float* __restrict__ out)
{
    const long long gid = (long long)blockIdx.x * blockDim.x + threadIdx.x;
    const long long wave = gid >> 6;
    const int lane = threadIdx.x & 63;
    if (wave >= (long long)NEDGE) return;
    const int b = (int)(wave / N_EDGES);
    const long long ebase = wave * 3;
    const int src = (int)ew[ebase + 0];
    const int dst = (int)ew[ebase + 1];
    const float w = ew[ebase + 2];
    atomicAdd(&out[((long long)b * N_NODES + src) * H_SIZE + lane],
              w * H[((long long)b * N_NODES + dst) * H_SIZE + lane]);
}

extern "C" void kernel_launch(void* const* d_in, const int* in_sizes, int n_in,
                              void* d_out, int out_size, void* d_ws, size_t ws_size,
                              hipStream_t stream) {
    const float* H  = (const float*)d_in[0];   // (B, N, 64) fp32
    const float* ew = (const float*)d_in[1];   // (B, E, 3) fp32
    float* out = (float*)d_out;                // (B, N, 64) fp32

    // ws layout: aux[NCHUNK*AUXW]ushort | (16B) pair[NCHUNK*CHUNK]int2 |
    //            (128B) Hb16[12.8M ushort]
    const size_t aux_bytes = (size_t)NCHUNK * AUXW * 2;
    const size_t p_off = (aux_bytes + 15) & ~(size_t)15;
    const size_t h_off = (p_off + (size_t)NCHUNK * CHUNK * 8 + 127) & ~(size_t)127;
    const size_t need_base = h_off;                     // ~17.6 MB (fp32 gather)
    const size_t need_full = h_off + (size_t)NHEL * 2;  // ~43.2 MB (bf16 gather)

    if (ws_size < need_base) {
        long long n = out_size;
        zero_kernel<<<(unsigned)((n + 255) / 256), 256, 0, stream>>>((int*)out, n);
        const long long total = (long long)NEDGE * 64;
        atomic_kernel<<<(unsigned)((total + 255) / 256), 256, 0, stream>>>(H, ew, out);
        return;
    }

    ushort* aux = (ushort*)d_ws;
    int2* pair  = (int2*)((char*)d_ws + p_off);
    ushort* Hb16 = (ushort*)((char*)d_ws + h_off);

    const bool full = (ws_size >= need_full);

    bin_kernel<<<NCHUNK, 512, 0, stream>>>(ew, aux, pair, H, Hb16, full ? 1 : 0);

    if (full) {
        sortgather_bf16<<<CB, 512, 0, stream>>>(Hb16, aux, pair, out);
    } else {
        sortgather_f32<<<CB, 512, 0, stream>>>(H, aux, pair, out);
    }
}

// Round 6
// 189.245 us; speedup vs baseline: 1.3964x; 1.0517x over previous
//
#include <hip/hip_runtime.h>

#define N_NODES 50000
#define BATCH   4
#define N_EDGES 500000
#define H_SIZE  64

#define NSEG   (BATCH * N_NODES)            // 200,000 segments (b, src)
#define NEDGE  (BATCH * N_EDGES)            // 2,000,000 edges
#define NHEL   ((long long)BATCH * N_NODES * H_SIZE)   // 12.8M H elems

#define SPB    128                          // segments per bucket (seg>>7)
#define CB     ((NSEG + SPB - 1) / SPB)     // 1563 buckets
#define CAP    2048                         // per-bucket LDS edge cap (mean 1280, +21 sigma)
#define CHUNK  4096                         // edges per bin block
#define NCHUNK ((NEDGE + CHUNK - 1) / CHUNK) // 489 (<512, fits one scan row)
#define AUXW   (CB + 1)                     // aux row: starts + sentinel
#define BINS   2048                         // padded bin count (>= CB+1)
#define PAIRN  ((long long)NCHUNK * CHUNK)  // allocated pair entries

// ---------- Phase 1: per-chunk bucket binning + fused H->bf16 cvt ----------
// (VERBATIM from R4, which passed at 199 us.)
// pair.x = (sl<<18) | gdst  where sl = seg&127, gdst = b*N_NODES+dst (<2^18)
__global__ __launch_bounds__(512) void bin_kernel(
    const float* __restrict__ ew, ushort* __restrict__ aux,
    int2* __restrict__ pair,
    const float* __restrict__ H, ushort* __restrict__ Hb16, int do_cvt)
{
    __shared__ int2 st[CHUNK];     // 32 KB sorted staging
    __shared__ int cnt[BINS];      // 8 KB
    __shared__ int scn[BINS];      // 8 KB (starts -> placement cursors)
    __shared__ int ttot[512];      // 2 KB scan temp
    const int c = blockIdx.x;
    const int tid = threadIdx.x;
    const int e0 = c * CHUNK;
    const int n = min(CHUNK, NEDGE - e0);

    for (int i = tid; i < BINS; i += 512) cnt[i] = 0;
    __syncthreads();

    // load up to 8 edges into regs + histogram
    int2 ev[8];
    int  ecb[8];
    int  myn = 0;
    for (int i = tid; i < n; i += 512) {
        long long eb = (long long)(e0 + i) * 3;
        int b = (e0 + i) / N_EDGES;
        int src = (int)ew[eb];
        int dst = (int)ew[eb + 1];
        float w = ew[eb + 2];
        src = min(max(src, 0), N_NODES - 1);
        dst = min(max(dst, 0), N_NODES - 1);
        int seg = b * N_NODES + src;
        int cb = seg >> 7, sl = seg & (SPB - 1);
        int2 v; v.x = (sl << 18) | (b * N_NODES + dst); v.y = __float_as_int(w);
        ev[myn] = v; ecb[myn] = cb; ++myn;
        atomicAdd(&cnt[cb], 1);
    }
    __syncthreads();

    // exclusive scan of 2048 bins: 4 bins/thread + 512-wide scan
    int c0 = cnt[4 * tid], c1 = cnt[4 * tid + 1];
    int c2 = cnt[4 * tid + 2], c3 = cnt[4 * tid + 3];
    int s0 = c0, s01 = c0 + c1, s012 = s01 + c2, tot = s012 + c3;
    ttot[tid] = tot;
    __syncthreads();
    for (int off = 1; off < 512; off <<= 1) {
        int t = (tid >= off) ? ttot[tid - off] : 0;
        __syncthreads();
        ttot[tid] += t;
        __syncthreads();
    }
    int base = ttot[tid] - tot;
    scn[4 * tid]     = base;
    scn[4 * tid + 1] = base + s0;
    scn[4 * tid + 2] = base + s01;
    scn[4 * tid + 3] = base + s012;
    __syncthreads();

    // write chunk-local bucket starts (before cursors get consumed)
    for (int i = tid; i < AUXW; i += 512)
        aux[(long long)c * AUXW + i] = (ushort)scn[i];
    __syncthreads();

    // place edges into sorted LDS staging
    for (int k = 0; k < myn; ++k) {
        int pos = atomicAdd(&scn[ecb[k]], 1);
        st[min(pos, CHUNK - 1)] = ev[k];
    }
    __syncthreads();

    // coalesced writeout (2 edges = int4 per op)
    for (int i = 2 * tid; i + 1 < n; i += 1024)
        *(int4*)(pair + (long long)e0 + i) = *(const int4*)(st + i);
    if (tid == 0 && (n & 1)) pair[(long long)e0 + n - 1] = st[n - 1];

    // fused cvt: H fp32 -> bf16 (RNE), grid-stride
    if (do_cvt) {
        const long long stride = (long long)NCHUNK * 512 * 4;
        for (long long i = ((long long)c * 512 + tid) * 4; i < NHEL; i += stride) {
            float4 f = *(const float4*)(H + i);
            ushort4 u;
            uint v;
            v = __float_as_uint(f.x); u.x = (ushort)((v + 0x7FFF + ((v >> 16) & 1)) >> 16);
            v = __float_as_uint(f.y); u.y = (ushort)((v + 0x7FFF + ((v >> 16) & 1)) >> 16);
            v = __float_as_uint(f.z); u.z = (ushort)((v + 0x7FFF + ((v >> 16) & 1)) >> 16);
            v = __float_as_uint(f.w); u.w = (ushort)((v + 0x7FFF + ((v >> 16) & 1)) >> 16);
            *(ushort4*)(Hb16 + i) = u;
        }
    }
}

// ---------- Phase 2: fused counting-sort (LDS) + register gather ----------
// R4 structure; copy phase replaced by hardened cooperative binary-search
// copy (no divergence, one flat global pass). Every derived index clamped.
__global__ __launch_bounds__(512) void sortgather_bf16(
    const ushort* __restrict__ Hb16, const ushort* __restrict__ aux,
    const int2* __restrict__ pair, float* __restrict__ out)
{
    __shared__ int2 spu[CAP];          // 16 KB unsorted staging
    __shared__ int2 sps[CAP];          // 16 KB sorted
    __shared__ int rb[512];            // inclusive run-length scan
    __shared__ int roff[512];          // run start offset within chunk
    __shared__ int cnt[SPB];
    __shared__ int scn[SPB];
    __shared__ int lcur[SPB];
    const int cb = blockIdx.x;
    const int tid = threadIdx.x;

    // run descriptor for chunk tid
    int off0 = 0, len = 0;
    if (tid < NCHUNK) {
        int a0 = (int)aux[(long long)tid * AUXW + cb];
        int a1 = (int)aux[(long long)tid * AUXW + cb + 1];
        a0 = min(a0, CHUNK); a1 = min(a1, CHUNK);
        off0 = a0; len = max(a1 - a0, 0);
    }
    roff[tid] = off0;
    rb[tid] = len;
    for (int i = tid; i < SPB; i += 512) { cnt[i] = 0; lcur[i] = 0; }
    __syncthreads();
    for (int off = 1; off < 512; off <<= 1) {
        int t = (tid >= off) ? rb[tid - off] : 0;
        __syncthreads();
        rb[tid] += t;
        __syncthreads();
    }
    const int nb = min(rb[511], CAP);

    // cooperative copy: edge i -> (chunk j, local) via binary search over rb
    for (int i = tid; i < nb; i += 512) {
        int j = 0;
        #pragma unroll
        for (int s = 256; s > 0; s >>= 1) {
            int k = j + s;
            if (k <= 512 && rb[k - 1] <= i) j = k;
        }
        j = min(j, 511);
        int prev = (j > 0) ? rb[j - 1] : 0;
        int local = i - prev;
        long long pidx = (long long)j * CHUNK + roff[j] + local;
        pidx = min(max(pidx, 0LL), PAIRN - 1);
        int2 v = pair[pidx];
        spu[i] = v;
        atomicAdd(&cnt[(v.x >> 18) & (SPB - 1)], 1);
    }
    __syncthreads();

    // exclusive scan of bins
    if (tid < SPB) scn[tid] = cnt[tid];
    __syncthreads();
    for (int off = 1; off < SPB; off <<= 1) {
        int t = (tid < SPB && tid >= off) ? scn[tid - off] : 0;
        __syncthreads();
        if (tid < SPB) scn[tid] += t;
        __syncthreads();
    }
    if (tid < SPB) scn[tid] -= cnt[tid];
    __syncthreads();

    // LDS -> LDS counting sort
    for (int i = tid; i < nb; i += 512) {
        int2 v = spu[i];
        int sl = (v.x >> 18) & (SPB - 1);
        int pos = scn[sl] + atomicAdd(&lcur[sl], 1);
        pos = min(max(pos, 0), CAP - 1);
        sps[pos] = v;
    }
    __syncthreads();

    // gather: wave w owns segments w*16 .. w*16+15
    const int wid  = tid >> 6;
    const int lane = tid & 63;
    const int half = lane >> 5;
    const int sub  = lane & 31;
    const uint* H32 = (const uint*)Hb16;

    for (int s = 0; s < 16; ++s) {
        int sl = wid * 16 + s;
        int st = scn[sl];
        int en = st + cnt[sl];
        float ax = 0.f, ay = 0.f;
        for (int i = st; i < en; i += 4) {
            int e0 = i + half;
            int e1 = i + 2 + half;
            int2 p0 = sps[(e0 < en) ? e0 : st];
            int2 p1 = sps[(e1 < en) ? e1 : st];
            uint a0 = ((uint)min(p0.x & 0x3FFFF, NSEG - 1) << 5) + sub;
            uint a1 = ((uint)min(p1.x & 0x3FFFF, NSEG - 1) << 5) + sub;
            uint h0 = H32[a0];
            uint h1 = H32[a1];
            float w0 = (e0 < en) ? __int_as_float(p0.y) : 0.0f;
            float w1 = (e1 < en) ? __int_as_float(p1.y) : 0.0f;
            ax = fmaf(w0, __uint_as_float(h0 << 16), ax);
            ay = fmaf(w0, __uint_as_float(h0 & 0xFFFF0000u), ay);
            ax = fmaf(w1, __uint_as_float(h1 << 16), ax);
            ay = fmaf(w1, __uint_as_float(h1 & 0xFFFF0000u), ay);
        }
        ax += __shfl_xor(ax, 32, 64);
        ay += __shfl_xor(ay, 32, 64);
        int seg = (cb << 7) + sl;
        if (half == 0 && seg < NSEG) {
            float2 v2; v2.x = ax; v2.y = ay;
            ((float2*)out)[((long long)seg << 5) + sub] = v2;
        }
    }
}

// fp32 variant (workspace too small for the bf16 mirror)
__global__ __launch_bounds__(512) void sortgather_f32(
    const float* __restrict__ H, const ushort* __restrict__ aux,
    const int2* __restrict__ pair, float* __restrict__ out)
{
    __shared__ int2 spu[CAP];
    __shared__ int2 sps[CAP];
    __shared__ int rb[512];
    __shared__ int roff[512];
    __shared__ int cnt[SPB];
    __shared__ int scn[SPB];
    __shared__ int lcur[SPB];
    const int cb = blockIdx.x;
    const int tid = threadIdx.x;

    int off0 = 0, len = 0;
    if (tid < NCHUNK) {
        int a0 = (int)aux[(long long)tid * AUXW + cb];
        int a1 = (int)aux[(long long)tid * AUXW + cb + 1];
        a0 = min(a0, CHUNK); a1 = min(a1, CHUNK);
        off0 = a0; len = max(a1 - a0, 0);
    }
    roff[tid] = off0;
    rb[tid] = len;
    for (int i = tid; i < SPB; i += 512) { cnt[i] = 0; lcur[i] = 0; }
    __syncthreads();
    for (int off = 1; off < 512; off <<= 1) {
        int t = (tid >= off) ? rb[tid - off] : 0;
        __syncthreads();
        rb[tid] += t;
        __syncthreads();
    }
    const int nb = min(rb[511], CAP);

    for (int i = tid; i < nb; i += 512) {
        int j = 0;
        #pragma unroll
        for (int s = 256; s > 0; s >>= 1) {
            int k = j + s;
            if (k <= 512 && rb[k - 1] <= i) j = k;
        }
        j = min(j, 511);
        int prev = (j > 0) ? rb[j - 1] : 0;
        int local = i - prev;
        long long pidx = (long long)j * CHUNK + roff[j] + local;
        pidx = min(max(pidx, 0LL), PAIRN - 1);
        int2 v = pair[pidx];
        spu[i] = v;
        atomicAdd(&cnt[(v.x >> 18) & (SPB - 1)], 1);
    }
    __syncthreads();

    if (tid < SPB) scn[tid] = cnt[tid];
    __syncthreads();
    for (int off = 1; off < SPB; off <<= 1) {
        int t = (tid < SPB && tid >= off) ? scn[tid - off] : 0;
        __syncthreads();
        if (tid < SPB) scn[tid] += t;
        __syncthreads();
    }
    if (tid < SPB) scn[tid] -= cnt[tid];
    __syncthreads();

    for (int i = tid; i < nb; i += 512) {
        int2 v = spu[i];
        int sl = (v.x >> 18) & (SPB - 1);
        int pos = scn[sl] + atomicAdd(&lcur[sl], 1);
        pos = min(max(pos, 0), CAP - 1);
        sps[pos] = v;
    }
    __syncthreads();

    const int wid  = tid >> 6;
    const int lane = tid & 63;
    const int half = lane >> 5;
    const int sub  = lane & 31;
    const float2* H2 = (const float2*)H;

    for (int s = 0; s < 16; ++s) {
        int sl = wid * 16 + s;
        int st = scn[sl];
        int en = st + cnt[sl];
        float ax = 0.f, ay = 0.f;
        for (int i = st; i < en; i += 4) {
            int e0 = i + half;
            int e1 = i + 2 + half;
            int2 p0 = sps[(e0 < en) ? e0 : st];
            int2 p1 = sps[(e1 < en) ? e1 : st];
            uint a0 = ((uint)min(p0.x & 0x3FFFF, NSEG - 1) << 5) + sub;
            uint a1 = ((uint)min(p1.x & 0x3FFFF, NSEG - 1) << 5) + sub;
            float2 h0 = H2[a0];
            float2 h1 = H2[a1];
            float w0 = (e0 < en) ? __int_as_float(p0.y) : 0.0f;
            float w1 = (e1 < en) ? __int_as_float(p1.y) : 0.0f;
            ax = fmaf(w0, h0.x, ax);
            ay = fmaf(w0, h0.y, ay);
            ax = fmaf(w1, h1.x, ax);
            ay = fmaf(w1, h1.y, ay);
        }
        ax += __shfl_xor(ax, 32, 64);
        ay += __shfl_xor(ay, 32, 64);
        int seg = (cb << 7) + sl;
        if (half == 0 && seg < NSEG) {
            float2 v2; v2.x = ax; v2.y = ay;
            ((float2*)out)[((long long)seg << 5) + sub] = v2;
        }
    }
}

// ---------- Fallback path (ws too small): zero + atomic scatter ----------
__global__ __launch_bounds__(256) void zero_kernel(int* __restrict__ p, long long n)
{
    long long i = (long long)blockIdx.x * blockDim.x + threadIdx.x;
    if (i < n) p[i] = 0;
}

__global__ __launch_bounds__(256) void atomic_kernel(
    const float* __restrict__ H, const float* __restrict__ ew,
    float* __restrict__ out)
{
    const long long gid = (long long)blockIdx.x * blockDim.x + threadIdx.x;
    const long long wave = gid >> 6;
    const int lane = threadIdx.x & 63;
    if (wave >= (long long)NEDGE) return;
    const int b = (int)(wave / N_EDGES);
    const long long ebase = wave * 3;
    const int src = (int)ew[ebase + 0];
    const int dst = (int)ew[ebase + 1];
    const float w = ew[ebase + 2];
    atomicAdd(&out[((long long)b * N_NODES + src) * H_SIZE + lane],
              w * H[((long long)b * N_NODES + dst) * H_SIZE + lane]);
}

extern "C" void kernel_launch(void* const* d_in, const int* in_sizes, int n_in,
                              void* d_out, int out_size, void* d_ws, size_t ws_size,
                              hipStream_t stream) {
    const float* H  = (const float*)d_in[0];   // (B, N, 64) fp32
    const float* ew = (const float*)d_in[1];   // (B, E, 3) fp32
    float* out = (float*)d_out;                // (B, N, 64) fp32

    // ws layout: aux[NCHUNK*AUXW]ushort | (16B) pair[NCHUNK*CHUNK]int2 |
    //            (128B) Hb16[12.8M ushort]
    const size_t aux_bytes = (size_t)NCHUNK * AUXW * 2;
    const size_t p_off = (aux_bytes + 15) & ~(size_t)15;
    const size_t h_off = (p_off + (size_t)PAIRN * 8 + 127) & ~(size_t)127;
    const size_t need_base = h_off;                     // ~17.6 MB (fp32 gather)
    const size_t need_full = h_off + (size_t)NHEL * 2;  // ~43.2 MB (bf16 gather)

    if (ws_size < need_base) {
        long long n = out_size;
        zero_kernel<<<(unsigned)((n + 255) / 256), 256, 0, stream>>>((int*)out, n);
        const long long total = (long long)NEDGE * 64;
        atomic_kernel<<<(unsigned)((total + 255) / 256), 256, 0, stream>>>(H, ew, out);
        return;
    }

    ushort* aux = (ushort*)d_ws;
    int2* pair  = (int2*)((char*)d_ws + p_off);
    ushort* Hb16 = (ushort*)((char*)d_ws + h_off);

    const bool full = (ws_size >= need_full);

    bin_kernel<<<NCHUNK, 512, 0, stream>>>(ew, aux, pair, H, Hb16, full ? 1 : 0);

    if (full) {
        sortgather_bf16<<<CB, 512, 0, stream>>>(Hb16, aux, pair, out);
    } else {
        sortgather_f32<<<CB, 512, 0, stream>>>(H, aux, pair, out);
    }
}

// Round 7
// 173.132 us; speedup vs baseline: 1.5264x; 1.0931x over previous
//
#include <hip/hip_runtime.h>

#define N_NODES 50000
#define BATCH   4
#define N_EDGES 500000
#define H_SIZE  64

#define NSEG   (BATCH * N_NODES)            // 200,000 segments (b, src)
#define NEDGE  (BATCH * N_EDGES)            // 2,000,000 edges
#define NHEL   ((long long)BATCH * N_NODES * H_SIZE)   // 12.8M H elems

#define SPB    128                          // segments per bucket (seg>>7)
#define CB     ((NSEG + SPB - 1) / SPB)     // 1563 buckets
#define CAP    2048                         // per-bucket LDS edge cap (mean 1280, +21 sigma)
#define CHUNK  4096                         // edges per bin block (= 8/thread exactly)
#define NCHUNK ((NEDGE + CHUNK - 1) / CHUNK) // 489 (<512, fits one scan row)
#define AUXW   (CB + 1)                     // aux row: starts + sentinel
#define BINS   2048                         // padded bin count (>= CB+1)
#define PAIRN  ((long long)NCHUNK * CHUNK)  // allocated pair entries

// ---------- Phase 1: per-chunk bucket binning + fused H->bf16 cvt ----------
// pair.x = (sl<<18) | gdst  where sl = seg&127, gdst = b*N_NODES+dst (<2^18)
// Edge regs indexed by COMPILE-TIME k (rule #20: no scratch). Scans are
// shfl-based (2 barriers instead of 20).
__global__ __launch_bounds__(512) void bin_kernel(
    const float* __restrict__ ew, ushort* __restrict__ aux,
    int2* __restrict__ pair,
    const float* __restrict__ H, ushort* __restrict__ Hb16, int do_cvt)
{
    __shared__ int2 st[CHUNK];     // 32 KB sorted staging
    __shared__ int cnt[BINS];      // 8 KB
    __shared__ int scn[BINS];      // 8 KB (starts -> placement cursors)
    __shared__ int wsum[8];
    const int c = blockIdx.x;
    const int tid = threadIdx.x;
    const int lane = tid & 63, wv = tid >> 6;
    const int e0 = c * CHUNK;
    const int n = min(CHUNK, NEDGE - e0);

    for (int i = tid; i < BINS; i += 512) cnt[i] = 0;
    __syncthreads();

    // exactly 8 edges per thread, compile-time indexed (no scratch)
    int2 ev[8];
    int  ecb[8];
    #pragma unroll
    for (int k = 0; k < 8; ++k) {
        int i = tid + 512 * k;
        if (i < n) {
            int e = e0 + i;
            long long eb = (long long)e * 3;
            int b = e / N_EDGES;
            int src = (int)ew[eb];
            int dst = (int)ew[eb + 1];
            float w = ew[eb + 2];
            src = min(max(src, 0), N_NODES - 1);
            dst = min(max(dst, 0), N_NODES - 1);
            int seg = b * N_NODES + src;
            int cb = seg >> 7, sl = seg & (SPB - 1);
            int2 v; v.x = (sl << 18) | (b * N_NODES + dst); v.y = __float_as_int(w);
            ev[k] = v; ecb[k] = cb;
            atomicAdd(&cnt[cb], 1);
        } else {
            ecb[k] = -1;
        }
    }
    __syncthreads();

    // exclusive scan of 2048 bins: 4 bins/thread + shfl wave scan
    int c0 = cnt[4 * tid], c1 = cnt[4 * tid + 1];
    int c2 = cnt[4 * tid + 2], c3 = cnt[4 * tid + 3];
    int s0 = c0, s01 = c0 + c1, s012 = s01 + c2, tot = s012 + c3;
    int iv = tot;
    #pragma unroll
    for (int off = 1; off < 64; off <<= 1) {
        int t = __shfl_up(iv, off, 64);
        if (lane >= off) iv += t;
    }
    if (lane == 63) wsum[wv] = iv;
    __syncthreads();
    int wbase = 0;
    #pragma unroll
    for (int k = 0; k < 8; ++k) wbase += (k < wv) ? wsum[k] : 0;
    int base = wbase + iv - tot;          // exclusive prefix of this thread's 4 bins
    scn[4 * tid]     = base;
    scn[4 * tid + 1] = base + s0;
    scn[4 * tid + 2] = base + s01;
    scn[4 * tid + 3] = base + s012;
    __syncthreads();

    // write chunk-local bucket starts (before cursors get consumed)
    for (int i = tid; i < AUXW; i += 512)
        aux[(long long)c * AUXW + i] = (ushort)scn[i];
    __syncthreads();

    // place edges into sorted LDS staging (compile-time k)
    #pragma unroll
    for (int k = 0; k < 8; ++k) {
        if (ecb[k] >= 0) {
            int pos = atomicAdd(&scn[ecb[k]], 1);
            st[min(pos, CHUNK - 1)] = ev[k];
        }
    }
    __syncthreads();

    // coalesced writeout (2 edges = int4 per op)
    for (int i = 2 * tid; i + 1 < n; i += 1024)
        *(int4*)(pair + (long long)e0 + i) = *(const int4*)(st + i);
    if (tid == 0 && (n & 1)) pair[(long long)e0 + n - 1] = st[n - 1];

    // fused cvt: H fp32 -> bf16 (RNE), grid-stride
    if (do_cvt) {
        const long long stride = (long long)NCHUNK * 512 * 4;
        for (long long i = ((long long)c * 512 + tid) * 4; i < NHEL; i += stride) {
            float4 f = *(const float4*)(H + i);
            ushort4 u;
            uint v;
            v = __float_as_uint(f.x); u.x = (ushort)((v + 0x7FFF + ((v >> 16) & 1)) >> 16);
            v = __float_as_uint(f.y); u.y = (ushort)((v + 0x7FFF + ((v >> 16) & 1)) >> 16);
            v = __float_as_uint(f.z); u.z = (ushort)((v + 0x7FFF + ((v >> 16) & 1)) >> 16);
            v = __float_as_uint(f.w); u.w = (ushort)((v + 0x7FFF + ((v >> 16) & 1)) >> 16);
            *(ushort4*)(Hb16 + i) = u;
        }
    }
}

// XCD-affinity bijective block->bucket map: each XCD (bid&7, assuming
// round-robin dispatch) gets a CONTIGUOUS bucket range, shrinking its
// Hb16 working set from 25.6 MB (all batches) to ~1 batch slice (6.4 MB).
// Bijective for CB = 8q + r (m204 form). Perf heuristic only.
__device__ __forceinline__ int swz_cb(int bid)
{
    const int q = CB >> 3, r = CB & 7;     // 195, 3
    int xcd = bid & 7, idx = bid >> 3;
    return (xcd < r) ? (xcd * (q + 1) + idx)
                     : (r * (q + 1) + (xcd - r) * q + idx);
}

// ---------- Phase 2: fused counting-sort (LDS) + register gather ----------
__global__ __launch_bounds__(512) void sortgather_bf16(
    const ushort* __restrict__ Hb16, const ushort* __restrict__ aux,
    const int2* __restrict__ pair, float* __restrict__ out)
{
    __shared__ int2 spu[CAP];          // 16 KB unsorted staging
    __shared__ int2 sps[CAP];          // 16 KB sorted
    __shared__ int rb[512];            // inclusive run-length scan
    __shared__ int roff[512];          // run start offset within chunk
    __shared__ int cnt[SPB];
    __shared__ int scn[SPB];
    __shared__ int lcur[SPB];
    __shared__ int wsum[8];
    const int cb = swz_cb(blockIdx.x);
    const int tid = threadIdx.x;
    const int lane = tid & 63, wv = tid >> 6;

    // run descriptor for chunk tid
    int off0 = 0, len = 0;
    if (tid < NCHUNK) {
        int a0 = (int)aux[(long long)tid * AUXW + cb];
        int a1 = (int)aux[(long long)tid * AUXW + cb + 1];
        a0 = min(a0, CHUNK); a1 = min(a1, CHUNK);
        off0 = a0; len = max(a1 - a0, 0);
    }
    roff[tid] = off0;
    for (int i = tid; i < SPB; i += 512) { cnt[i] = 0; lcur[i] = 0; }

    // shfl-based inclusive scan of run lengths -> rb[]
    int iv = len;
    #pragma unroll
    for (int off = 1; off < 64; off <<= 1) {
        int t = __shfl_up(iv, off, 64);
        if (lane >= off) iv += t;
    }
    if (lane == 63) wsum[wv] = iv;
    __syncthreads();
    int wbase = 0;
    #pragma unroll
    for (int k = 0; k < 8; ++k) wbase += (k < wv) ? wsum[k] : 0;
    rb[tid] = wbase + iv;
    __syncthreads();
    const int nb = min(rb[511], CAP);

    // cooperative copy: edge i -> (chunk j, local) via binary search over rb
    for (int i = tid; i < nb; i += 512) {
        int j = 0;
        #pragma unroll
        for (int s = 256; s > 0; s >>= 1) {
            int k = j + s;
            if (k <= 512 && rb[k - 1] <= i) j = k;
        }
        j = min(j, 511);
        int prev = (j > 0) ? rb[j - 1] : 0;
        int local = i - prev;
        long long pidx = (long long)j * CHUNK + roff[j] + local;
        pidx = min(max(pidx, 0LL), PAIRN - 1);
        int2 v = pair[pidx];
        spu[i] = v;
        atomicAdd(&cnt[(v.x >> 18) & (SPB - 1)], 1);
    }
    __syncthreads();

    // exclusive scan of SPB bins (waves 0-1 shfl scan + cross-wave base)
    int cv = (tid < SPB) ? cnt[tid] : 0;
    int iv2 = cv;
    #pragma unroll
    for (int off = 1; off < 64; off <<= 1) {
        int t = __shfl_up(iv2, off, 64);
        if (lane >= off) iv2 += t;
    }
    if (tid == 63) wsum[0] = iv2;
    __syncthreads();
    if (tid < SPB) scn[tid] = iv2 - cv + ((tid >= 64) ? wsum[0] : 0);
    __syncthreads();

    // LDS -> LDS counting sort
    for (int i = tid; i < nb; i += 512) {
        int2 v = spu[i];
        int sl = (v.x >> 18) & (SPB - 1);
        int pos = scn[sl] + atomicAdd(&lcur[sl], 1);
        pos = min(max(pos, 0), CAP - 1);
        sps[pos] = v;
    }
    __syncthreads();

    // gather: wave w owns segments w*16 .. w*16+15
    const int wid  = tid >> 6;
    const int half = lane >> 5;
    const int sub  = lane & 31;
    const uint* H32 = (const uint*)Hb16;

    for (int s = 0; s < 16; ++s) {
        int sl = wid * 16 + s;
        int st = scn[sl];
        int en = st + cnt[sl];
        float ax = 0.f, ay = 0.f;
        for (int i = st; i < en; i += 4) {
            int e0 = i + half;
            int e1 = i + 2 + half;
            int2 p0 = sps[(e0 < en) ? e0 : st];
            int2 p1 = sps[(e1 < en) ? e1 : st];
            uint a0 = ((uint)min(p0.x & 0x3FFFF, NSEG - 1) << 5) + sub;
            uint a1 = ((uint)min(p1.x & 0x3FFFF, NSEG - 1) << 5) + sub;
            uint h0 = H32[a0];
            uint h1 = H32[a1];
            float w0 = (e0 < en) ? __int_as_float(p0.y) : 0.0f;
            float w1 = (e1 < en) ? __int_as_float(p1.y) : 0.0f;
            ax = fmaf(w0, __uint_as_float(h0 << 16), ax);
            ay = fmaf(w0, __uint_as_float(h0 & 0xFFFF0000u), ay);
            ax = fmaf(w1, __uint_as_float(h1 << 16), ax);
            ay = fmaf(w1, __uint_as_float(h1 & 0xFFFF0000u), ay);
        }
        ax += __shfl_xor(ax, 32, 64);
        ay += __shfl_xor(ay, 32, 64);
        int seg = (cb << 7) + sl;
        if (half == 0 && seg < NSEG) {
            float2 v2; v2.x = ax; v2.y = ay;
            ((float2*)out)[((long long)seg << 5) + sub] = v2;
        }
    }
}

// fp32 variant (workspace too small for the bf16 mirror)
__global__ __launch_bounds__(512) void sortgather_f32(
    const float* __restrict__ H, const ushort* __restrict__ aux,
    const int2* __restrict__ pair, float* __restrict__ out)
{
    __shared__ int2 spu[CAP];
    __shared__ int2 sps[CAP];
    __shared__ int rb[512];
    __shared__ int roff[512];
    __shared__ int cnt[SPB];
    __shared__ int scn[SPB];
    __shared__ int lcur[SPB];
    __shared__ int wsum[8];
    const int cb = swz_cb(blockIdx.x);
    const int tid = threadIdx.x;
    const int lane = tid & 63, wv = tid >> 6;

    int off0 = 0, len = 0;
    if (tid < NCHUNK) {
        int a0 = (int)aux[(long long)tid * AUXW + cb];
        int a1 = (int)aux[(long long)tid * AUXW + cb + 1];
        a0 = min(a0, CHUNK); a1 = min(a1, CHUNK);
        off0 = a0; len = max(a1 - a0, 0);
    }
    roff[tid] = off0;
    for (int i = tid; i < SPB; i += 512) { cnt[i] = 0; lcur[i] = 0; }

    int iv = len;
    #pragma unroll
    for (int off = 1; off < 64; off <<= 1) {
        int t = __shfl_up(iv, off, 64);
        if (lane >= off) iv += t;
    }
    if (lane == 63) wsum[wv] = iv;
    __syncthreads();
    int wbase = 0;
    #pragma unroll
    for (int k = 0; k < 8; ++k) wbase += (k < wv) ? wsum[k] : 0;
    rb[tid] = wbase + iv;
    __syncthreads();
    const int nb = min(rb[511], CAP);

    for (int i = tid; i < nb; i += 512) {
        int j = 0;
        #pragma unroll
        for (int s = 256; s > 0; s >>= 1) {
            int k = j + s;
            if (k <= 512 && rb[k - 1] <= i) j = k;
        }
        j = min(j, 511);
        int prev = (j > 0) ? rb[j - 1] : 0;
        int local = i - prev;
        long long pidx = (long long)j * CHUNK + roff[j] + local;
        pidx = min(max(pidx, 0LL), PAIRN - 1);
        int2 v = pair[pidx];
        spu[i] = v;
        atomicAdd(&cnt[(v.x >> 18) & (SPB - 1)], 1);
    }
    __syncthreads();

    int cv = (tid < SPB) ? cnt[tid] : 0;
    int iv2 = cv;
    #pragma unroll
    for (int off = 1; off < 64; off <<= 1) {
        int t = __shfl_up(iv2, off, 64);
        if (lane >= off) iv2 += t;
    }
    if (tid == 63) wsum[0] = iv2;
    __syncthreads();
    if (tid < SPB) scn[tid] = iv2 - cv + ((tid >= 64) ? wsum[0] : 0);
    __syncthreads();

    for (int i = tid; i < nb; i += 512) {
        int2 v = spu[i];
        int sl = (v.x >> 18) & (SPB - 1);
        int pos = scn[sl] + atomicAdd(&lcur[sl], 1);
        pos = min(max(pos, 0), CAP - 1);
        sps[pos] = v;
    }
    __syncthreads();

    const int wid  = tid >> 6;
    const int half = lane >> 5;
    const int sub  = lane & 31;
    const float2* H2 = (const float2*)H;

    for (int s = 0; s < 16; ++s) {
        int sl = wid * 16 + s;
        int st = scn[sl];
        int en = st + cnt[sl];
        float ax = 0.f, ay = 0.f;
        for (int i = st; i < en; i += 4) {
            int e0 = i + half;
            int e1 = i + 2 + half;
            int2 p0 = sps[(e0 < en) ? e0 : st];
            int2 p1 = sps[(e1 < en) ? e1 : st];
            uint a0 = ((uint)min(p0.x & 0x3FFFF, NSEG - 1) << 5) + sub;
            uint a1 = ((uint)min(p1.x & 0x3FFFF, NSEG - 1) << 5) + sub;
            float2 h0 = H2[a0];
            float2 h1 = H2[a1];
            float w0 = (e0 < en) ? __int_as_float(p0.y) : 0.0f;
            float w1 = (e1 < en) ? __int_as_float(p1.y) : 0.0f;
            ax = fmaf(w0, h0.x, ax);
            ay = fmaf(w0, h0.y, ay);
            ax = fmaf(w1, h1.x, ax);
            ay = fmaf(w1, h1.y, ay);
        }
        ax += __shfl_xor(ax, 32, 64);
        ay += __shfl_xor(ay, 32, 64);
        int seg = (cb << 7) + sl;
        if (half == 0 && seg < NSEG) {
            float2 v2; v2.x = ax; v2.y = ay;
            ((float2*)out)[((long long)seg << 5) + sub] = v2;
        }
    }
}

// ---------- Fallback path (ws too small): zero + atomic scatter ----------
__global__ __launch_bounds__(256) void zero_kernel(int* __restrict__ p, long long n)
{
    long long i = (long long)blockIdx.x * blockDim.x + threadIdx.x;
    if (i < n) p[i] = 0;
}

__global__ __launch_bounds__(256) void atomic_kernel(
    const float* __restrict__ H, const float* __restrict__ ew,
    float* __restrict__ out)
{
    const long long gid = (long long)blockIdx.x * blockDim.x + threadIdx.x;
    const long long wave = gid >> 6;
    const int lane = threadIdx.x & 63;
    if (wave >= (long long)NEDGE) return;
    const int b = (int)(wave / N_EDGES);
    const long long ebase = wave * 3;
    const int src = (int)ew[ebase + 0];
    const int dst = (int)ew[ebase + 1];
    const float w = ew[ebase + 2];
    atomicAdd(&out[((long long)b * N_NODES + src) * H_SIZE + lane],
              w * H[((long long)b * N_NODES + dst) * H_SIZE + lane]);
}

extern "C" void kernel_launch(void* const* d_in, const int* in_sizes, int n_in,
                              void* d_out, int out_size, void* d_ws, size_t ws_size,
                              hipStream_t stream) {
    const float* H  = (const float*)d_in[0];   // (B, N, 64) fp32
    const float* ew = (const float*)d_in[1];   // (B, E, 3) fp32
    float* out = (float*)d_out;                // (B, N, 64) fp32

    // ws layout: aux[NCHUNK*AUXW]ushort | (16B) pair[NCHUNK*CHUNK]int2 |
    //            (128B) Hb16[12.8M ushort]
    const size_t aux_bytes = (size_t)NCHUNK * AUXW * 2;
    const size_t p_off = (aux_bytes + 15) & ~(size_t)15;
    const size_t h_off = (p_off + (size_t)PAIRN * 8 + 127) & ~(size_t)127;
    const size_t need_base = h_off;                     // ~17.6 MB (fp32 gather)
    const size_t need_full = h_off + (size_t)NHEL * 2;  // ~43.2 MB (bf16 gather)

    if (ws_size < need_base) {
        long long n = out_size;
        zero_kernel<<<(unsigned)((n + 255) / 256), 256, 0, stream>>>((int*)out, n);
        const long long total = (long long)NEDGE * 64;
        atomic_kernel<<<(unsigned)((total + 255) / 256), 256, 0, stream>>>(H, ew, out);
        return;
    }

    ushort* aux = (ushort*)d_ws;
    int2* pair  = (int2*)((char*)d_ws + p_off);
    ushort* Hb16 = (ushort*)((char*)d_ws + h_off);

    const bool full = (ws_size >= need_full);

    bin_kernel<<<NCHUNK, 512, 0, stream>>>(ew, aux, pair, H, Hb16, full ? 1 : 0);

    if (full) {
        sortgather_bf16<<<CB, 512, 0, stream>>>(Hb16, aux, pair, out);
    } else {
        sortgather_f32<<<CB, 512, 0, stream>>>(H, aux, pair, out);
    }
}